// Round 5
// baseline (373.051 us; speedup 1.0000x reference)
//
#include <hip/hip_runtime.h>
#include <hip/hip_bf16.h>

#define N_NODES 10000
#define N_EDGES 320000
#define N_GRAPHS 64
#define DIM 256
#define ADIM 118
#define OUTD 100
#define CAP 96           // fixed CSR slots per node (mean degree 32, max ~66)
#define CURPAD 16        // ints per cursor slot -> one 64B line per counter

typedef short bf8_t __attribute__((ext_vector_type(8)));
typedef float f4_t  __attribute__((ext_vector_type(4)));

__device__ __forceinline__ unsigned short f2bf(float f) {
    unsigned u = __float_as_uint(f);
    u += 0x7FFFu + ((u >> 16) & 1u);   // round-to-nearest-even
    return (unsigned short)(u >> 16);
}
__device__ __forceinline__ float bf2f(unsigned short s) {
    return __uint_as_float(((unsigned)s) << 16);
}

// ---------- setup: weight conversion + cursor init + feat zero ----------
__global__ __launch_bounds__(256) void convW_k(
    const float* __restrict__ Wn, const float* __restrict__ Wg,
    unsigned short* __restrict__ WnT, unsigned short* __restrict__ WgT,
    int* __restrict__ cursor, float* __restrict__ feat) {
    int i = blockIdx.x * 256 + threadIdx.x;   // grid 640*256 = 163840
    if (i < 32768) {
        int c = i >> 7, k = i & 127;
        WnT[i] = (k < ADIM) ? f2bf(Wn[k * DIM + c]) : (unsigned short)0;
    } else {
        int j = i - 32768;
        int l = j >> 16, rem = j & 65535;
        int c = rem >> 8, k = rem & 255;
        WgT[j] = f2bf(Wg[l * 65536 + k * DIM + c]);
    }
    if (i < N_NODES * CURPAD) cursor[i] = (i >> 4) * CAP;  // only slot 0 of each line used
    if (i < N_GRAPHS * DIM) feat[i] = 0.f;
}

// ---------- CSR fill (fixed stride); cursor padded to 1 counter / cacheline ----------
__global__ __launch_bounds__(256) void fill_k(
    const int* __restrict__ src, const int* __restrict__ dst,
    const float* __restrict__ len, int* __restrict__ cursor,
    int2* __restrict__ epack) {
    int j = blockIdx.x * 256 + threadIdx.x;
    if (j >= N_EDGES) return;
    int d = dst[j];
    int pos = atomicAdd(&cursor[d << 4], 1);
    if (pos < d * CAP + CAP)
        epack[pos] = make_int2(src[j], __float_as_int(len[j]));
}

// ---------- node embedding via MFMA: h = bf16(an @ W_node + b_node) ----------
#define AST 136   // LDS row stride (ushorts)
__global__ __launch_bounds__(256) void node_embed_k(
    const float* __restrict__ an, const unsigned short* __restrict__ WnT,
    const float* __restrict__ bn, unsigned short* __restrict__ hbf) {
    __shared__ __attribute__((aligned(16))) unsigned short xs[16 * AST];
    const int base = blockIdx.x * 16;
    const int tid = threadIdx.x;
    for (int i = tid; i < 16 * (AST - ADIM); i += 256) {
        int r = i / (AST - ADIM);
        int c = i - r * (AST - ADIM);
        xs[r * AST + ADIM + c] = 0;
    }
    for (int i = tid; i < 16 * 59; i += 256) {   // 118 = 2*59, float2 loads
        int r = i / 59;
        int c = (i - r * 59) * 2;
        float2 v = *(const float2*)(an + (size_t)(base + r) * ADIM + c);
        xs[r * AST + c]     = f2bf(v.x);
        xs[r * AST + c + 1] = f2bf(v.y);
    }
    __syncthreads();
    const int wave = tid >> 6, lane = tid & 63;
    const int m = lane & 15, quad = lane >> 4;
    bf8_t afrag[4];
    #pragma unroll
    for (int s = 0; s < 4; ++s)
        afrag[s] = *(const bf8_t*)&xs[m * AST + s * 32 + quad * 8];
    const int colbase = wave * 64;
    #pragma unroll
    for (int ct = 0; ct < 4; ++ct) {
        f4_t acc = (f4_t){0.f, 0.f, 0.f, 0.f};
        const unsigned short* wp = WnT + (size_t)(colbase + ct * 16 + m) * 128 + quad * 8;
        #pragma unroll
        for (int s = 0; s < 4; ++s) {
            bf8_t bfrag = *(const bf8_t*)(wp + s * 32);
            acc = __builtin_amdgcn_mfma_f32_16x16x32_bf16(afrag[s], bfrag, acc, 0, 0, 0);
        }
        int col = colbase + ct * 16 + m;
        float bb = bn[col];
        #pragma unroll
        for (int r = 0; r < 4; ++r)
            hbf[(size_t)(base + quad * 4 + r) * DIM + col] = f2bf(acc[r] + bb);
    }
}

// ---------- gather (R3 structure) with diagnostic rep loop ----------
// Block B -> XCD B%8. half = (B>>2)&1: XCDs 0-3 touch dims [0,128) of hbf,
// XCDs 4-7 dims [128,256). 4 waves/block, 1 node/wave, 4 edges in flight.
// rep>1 repeats the whole body idempotently (diagnostic timing only).
__global__ __launch_bounds__(256) void gather_k(
    const unsigned short* __restrict__ hbf, const int* __restrict__ cursor,
    const int2* __restrict__ epack, const float* __restrict__ We,
    const float* __restrict__ be, const float* __restrict__ epsp, int layer,
    unsigned short* __restrict__ xbf, int rep) {
    const int B = blockIdx.x;                 // grid = 5000
    const int half = (B >> 2) & 1;
    const int k = (B >> 3) * 4 + (B & 3);     // node tile [0, 2500)
    const int wave = threadIdx.x >> 6, lane = threadIdx.x & 63;
    const int node = __builtin_amdgcn_readfirstlane(k * 4 + wave);
    const int sub = lane >> 4;                // which of 4 concurrent edges
    const int dp = half * 128 + (lane & 15) * 8;   // this lane's 8 dims
    float4 wa = *(const float4*)(We + dp);
    float4 wc = *(const float4*)(We + dp + 4);
    float4 b0 = *(const float4*)(be + dp);
    float4 b1 = *(const float4*)(be + dp + 4);
    float w[8]  = {wa.x, wa.y, wa.z, wa.w, wc.x, wc.y, wc.z, wc.w};
    float bv[8] = {b0.x, b0.y, b0.z, b0.w, b1.x, b1.y, b1.z, b1.w};
    const float eps1 = 1.f + epsp[layer];
    for (int r = 0; r < rep; ++r) {
        asm volatile("" ::: "memory");        // keep each rep live (no cross-rep DCE)
        float acc[8];
        #pragma unroll
        for (int i = 0; i < 8; ++i) acc[i] = 0.f;
        const unsigned short* hb = hbf + dp;
        const int lo = node * CAP;
        const int cnt = min(__builtin_amdgcn_readfirstlane(cursor[node * CURPAD]) - lo, CAP);
        const int2* ep = epack + lo;
#define GATH(q) { \
    bf8_t a = *(const bf8_t*)(hb + (size_t)(q).x * DIM); \
    float l = __int_as_float((q).y); \
    _Pragma("unroll") \
    for (int d = 0; d < 8; ++d) \
        acc[d] += fmaxf(bf2f((unsigned short)a[d]) + fmaf(l, w[d], bv[d]), 0.f); }
        int t = 0;
        for (; t + 7 < cnt; t += 8) {
            int2 qa = ep[t + sub], qb = ep[t + 4 + sub];
            GATH(qa) GATH(qb)
        }
        for (; t + 3 < cnt; t += 4) {
            int2 q = ep[t + sub];
            GATH(q)
        }
        if (t < cnt && t + sub < cnt) {       // partial group: exec-masked
            int2 q = ep[t + sub];
            GATH(q)
        }
#undef GATH
        // reduce the 4 edge-groups (same dims) across quarter-waves
        #pragma unroll
        for (int d = 0; d < 8; ++d) {
            acc[d] += __shfl(acc[d], lane ^ 16, 64);
            acc[d] += __shfl(acc[d], lane ^ 32, 64);
        }
        if (sub == 0) {
            bf8_t hv = *(const bf8_t*)(hbf + (size_t)node * DIM + dp);
            bf8_t o;
            #pragma unroll
            for (int d = 0; d < 8; ++d)
                o[d] = (short)f2bf(fmaf(eps1, bf2f((unsigned short)hv[d]), acc[d]));
            *(bf8_t*)(xbf + (size_t)node * DIM + dp) = o;
        }
    }
}

// ---------- MFMA node update: block = 16 rows x 128 cols (grid 1250) ----------
// rep>1 repeats idempotently (only used with do_pool=0).
#define XST 264   // LDS row stride (ushorts)
__global__ __launch_bounds__(256) void update_k(
    const unsigned short* __restrict__ xbf,
    const unsigned short* __restrict__ WT, const float* __restrict__ b,
    unsigned short* __restrict__ hout,
    const int* __restrict__ gid, float* __restrict__ feat, int do_pool, int rep) {
    __shared__ __attribute__((aligned(16))) unsigned short xs[16 * XST];
    __shared__ int gids[16];
    const int rb = blockIdx.x >> 1;
    const int halfc = blockIdx.x & 1;
    const int base = rb * 16;
    const int tid = threadIdx.x;
    const int wave = tid >> 6, lane = tid & 63;
    const int m = lane & 15, quad = lane >> 4;
    for (int r = 0; r < rep; ++r) {
        asm volatile("" ::: "memory");        // keep each rep live
        #pragma unroll
        for (int cch = tid; cch < 512; cch += 256) {     // 16 rows x 32 chunks of 8
            int rr = cch >> 5, k0 = (cch & 31) * 8;
            *(bf8_t*)&xs[rr * XST + k0] = *(const bf8_t*)(xbf + (size_t)(base + rr) * DIM + k0);
        }
        if (do_pool && tid < 16) gids[tid] = gid[base + tid];
        __syncthreads();
        bf8_t afrag[8];
        #pragma unroll
        for (int s = 0; s < 8; ++s)
            afrag[s] = *(const bf8_t*)&xs[m * XST + s * 32 + quad * 8];
        const int colbase = halfc * 128 + wave * 32;
        #pragma unroll
        for (int ct = 0; ct < 2; ++ct) {
            const int col = colbase + ct * 16 + m;
            f4_t acc2 = (f4_t){0.f, 0.f, 0.f, 0.f};
            const unsigned short* wp = WT + (size_t)col * DIM + quad * 8;
            #pragma unroll
            for (int s = 0; s < 8; ++s) {
                bf8_t bfrag = *(const bf8_t*)(wp + s * 32);
                acc2 = __builtin_amdgcn_mfma_f32_16x16x32_bf16(afrag[s], bfrag, acc2, 0, 0, 0);
            }
            const float bb = b[col];
            if (!do_pool) {
                #pragma unroll
                for (int r2 = 0; r2 < 4; ++r2)
                    hout[(size_t)(base + quad * 4 + r2) * DIM + col] = f2bf(acc2[r2] + bb);
            } else {
                if (gids[0] == gids[15]) {
                    float v = acc2[0] + acc2[1] + acc2[2] + acc2[3] + 4.f * bb;
                    v += __shfl(v, lane ^ 16, 64);
                    v += __shfl(v, lane ^ 32, 64);   // sum across the 4 quads
                    if (quad == 0) atomicAdd(&feat[(size_t)gids[0] * DIM + col], v);
                } else {
                    float run = 0.f;
                    int cur = gids[quad * 4];
                    #pragma unroll
                    for (int r2 = 0; r2 < 4; ++r2) {
                        int g = gids[quad * 4 + r2];
                        if (g != cur) {
                            atomicAdd(&feat[(size_t)cur * DIM + col], run);
                            run = 0.f;
                            cur = g;
                        }
                        run += acc2[r2] + bb;
                    }
                    atomicAdd(&feat[(size_t)cur * DIM + col], run);
                }
            }
        }
        __syncthreads();   // protect xs across reps
    }
}

// ---------- fused global minmax + normalize + head (one block per graph) ----------
__global__ __launch_bounds__(256) void headmm_k(
    const float* __restrict__ feat, const float* __restrict__ Wm,
    const float* __restrict__ bm, const float* __restrict__ epsp,
    float* __restrict__ out) {
    __shared__ float frow[DIM];
    __shared__ float smn[4], smx[4], sMn, sMx;
    const int g = blockIdx.x;
    const int tid = threadIdx.x;
    float mn = 3.4e38f, mx = -3.4e38f;
    for (int i = tid; i < N_GRAPHS * DIM; i += 256) {
        float v = feat[i];
        mn = fminf(mn, v);
        mx = fmaxf(mx, v);
    }
    frow[tid] = feat[g * DIM + tid];
    #pragma unroll
    for (int off = 32; off > 0; off >>= 1) {
        mn = fminf(mn, __shfl_down(mn, off, 64));
        mx = fmaxf(mx, __shfl_down(mx, off, 64));
    }
    const int wave = tid >> 6, lane = tid & 63;
    if (lane == 0) { smn[wave] = mn; smx[wave] = mx; }
    __syncthreads();
    if (tid == 0) {
        sMn = fminf(fminf(smn[0], smn[1]), fminf(smn[2], smn[3]));
        sMx = fmaxf(fmaxf(smx[0], smx[1]), fmaxf(smx[2], smx[3]));
    }
    __syncthreads();
    if (tid < OUTD) {
        const float mnv = sMn;
        const float inv = 1.f / (epsp[0] + sMx - mnv);
        float acc = 0.f;
        for (int d = 0; d < DIM; ++d)
            acc += (frow[d] - mnv) * Wm[d * OUTD + tid];
        out[g * OUTD + tid] = acc * inv + bm[tid];
    }
}

extern "C" void kernel_launch(void* const* d_in, const int* in_sizes, int n_in,
                              void* d_out, int out_size, void* d_ws, size_t ws_size,
                              hipStream_t stream) {
    const float* atomic_num = (const float*)d_in[0];
    const float* length     = (const float*)d_in[1];
    const int*   src        = (const int*)d_in[2];
    const int*   dst        = (const int*)d_in[3];
    const int*   gid        = (const int*)d_in[4];
    const float* W_node     = (const float*)d_in[5];
    const float* b_node     = (const float*)d_in[6];
    const float* W_edge     = (const float*)d_in[7];
    const float* b_edge     = (const float*)d_in[8];
    const float* gine_eps   = (const float*)d_in[9];
    const float* W_gnn      = (const float*)d_in[10];
    const float* b_gnn      = (const float*)d_in[11];
    const float* eps_param  = (const float*)d_in[12];
    const float* W_mlp      = (const float*)d_in[13];
    const float* b_mlp      = (const float*)d_in[14];
    float* out = (float*)d_out;

    // workspace (~24 MB)
    float* feat = (float*)d_ws;                                   // G*D
    int* cursor = (int*)(feat + (size_t)N_GRAPHS * DIM);          // N*CURPAD
    int2* epack = (int2*)(cursor + (size_t)N_NODES * CURPAD + 16);// N*CAP
    unsigned short* hbf0 = (unsigned short*)(epack + (size_t)N_NODES * CAP); // [N][256]
    unsigned short* hbf1 = hbf0 + (size_t)N_NODES * DIM;          // [N][256]
    unsigned short* xbf  = hbf1 + (size_t)N_NODES * DIM;          // [N][256]
    unsigned short* WnT  = xbf + (size_t)N_NODES * DIM;           // 256*128
    unsigned short* WgT  = WnT + 256 * 128;                       // 2*256*256

    convW_k<<<640, 256, 0, stream>>>(W_node, W_gnn, WnT, WgT, cursor, feat);
    fill_k<<<N_EDGES / 256, 256, 0, stream>>>(src, dst, length, cursor, epack);
    node_embed_k<<<N_NODES / 16, 256, 0, stream>>>(atomic_num, WnT, b_node, hbf0);

    // GINE layer 0: hbf0 -> xbf -> hbf1  (DIAGNOSTIC: rep=8, idempotent)
    gather_k<<<5000, 256, 0, stream>>>(
        hbf0, cursor, epack, W_edge, b_edge, gine_eps, 0, xbf, 8);
    update_k<<<(N_NODES / 16) * 2, 256, 0, stream>>>(
        xbf, WgT, b_gnn, hbf1, gid, feat, 0, 8);
    // GINE layer 1: hbf1 -> xbf -> feat (pooled), rep=1
    gather_k<<<5000, 256, 0, stream>>>(
        hbf1, cursor, epack, W_edge, b_edge, gine_eps, 1, xbf, 1);
    update_k<<<(N_NODES / 16) * 2, 256, 0, stream>>>(
        xbf, WgT + 256 * 256, b_gnn + DIM, hbf0, gid, feat, 1, 1);

    // fused minmax + normalize + head
    headmm_k<<<N_GRAPHS, 256, 0, stream>>>(feat, W_mlp, b_mlp, eps_param, out);
}

// Round 6
// 203.861 us; speedup vs baseline: 1.8299x; 1.8299x over previous
//
#include <hip/hip_runtime.h>
#include <hip/hip_bf16.h>

#define N_NODES 10000
#define N_EDGES 320000
#define N_GRAPHS 64
#define DIM 256
#define ADIM 118
#define OUTD 100
#define CAP 96           // fixed CSR slots per node (mean degree 32, max ~66)
#define CURPAD 16        // ints per counter slot -> one 64B line per counter

typedef short bf8_t __attribute__((ext_vector_type(8)));
typedef float f4_t  __attribute__((ext_vector_type(4)));
typedef float f2_t  __attribute__((ext_vector_type(2)));

__device__ __forceinline__ unsigned short f2bf(float f) {
    unsigned u = __float_as_uint(f);
    u += 0x7FFFu + ((u >> 16) & 1u);   // round-to-nearest-even
    return (unsigned short)(u >> 16);
}
__device__ __forceinline__ float bf2f(unsigned short s) {
    return __uint_as_float(((unsigned)s) << 16);
}
// VOP3P packed-f32 ops (2 floats / instruction) — gfx90a+/gfx950
__device__ __forceinline__ f2_t pk_fma(f2_t a, f2_t b, f2_t c) {
    f2_t d;
    asm("v_pk_fma_f32 %0, %1, %2, %3" : "=v"(d) : "v"(a), "v"(b), "v"(c));
    return d;
}
__device__ __forceinline__ f2_t pk_add(f2_t a, f2_t b) {
    f2_t d;
    asm("v_pk_add_f32 %0, %1, %2" : "=v"(d) : "v"(a), "v"(b));
    return d;
}

// ---------- fused setup: CSR fill (blocks 0-1249) + weight conversion ----------
// cnt[] and feat[] are pre-zeroed by hipMemsetAsync (adjacent at d_ws base).
__global__ __launch_bounds__(256) void setup_k(
    const int* __restrict__ src, const int* __restrict__ dst,
    const float* __restrict__ len,
    const float* __restrict__ Wn, const float* __restrict__ Wg,
    unsigned short* __restrict__ WnT, unsigned short* __restrict__ WgT,
    int* __restrict__ cnt, int2* __restrict__ epack) {
    const int B = blockIdx.x;
    const int tid = threadIdx.x;
    if (B < 1250) {                       // 1250*256 = 320000 edges exactly
        int j = B * 256 + tid;
        int d = dst[j];
        int pos = atomicAdd(&cnt[d << 4], 1);
        if (pos < CAP)
            epack[d * CAP + pos] = make_int2(src[j] * DIM, __float_as_int(len[j]));
    } else {                              // 640 blocks of weight conversion
        int i = (B - 1250) * 256 + tid;   // < 163840
        if (i < 32768) {
            int c = i >> 7, k = i & 127;
            WnT[i] = (k < ADIM) ? f2bf(Wn[k * DIM + c]) : (unsigned short)0;
        } else {
            int j = i - 32768;
            int l = j >> 16, rem = j & 65535;
            int c = rem >> 8, k = rem & 255;
            WgT[j] = f2bf(Wg[l * 65536 + k * DIM + c]);
        }
    }
}

// ---------- node embedding via MFMA: hbf = bf16(an @ W_node + b_node + b_edge) ----------
// (b_edge folded in so the gather's per-edge math is a single pk_fma)
#define AST 136   // LDS row stride (ushorts)
__global__ __launch_bounds__(256) void node_embed_k(
    const float* __restrict__ an, const unsigned short* __restrict__ WnT,
    const float* __restrict__ bn, const float* __restrict__ be,
    unsigned short* __restrict__ hbf) {
    __shared__ __attribute__((aligned(16))) unsigned short xs[16 * AST];
    const int base = blockIdx.x * 16;
    const int tid = threadIdx.x;
    for (int i = tid; i < 16 * (AST - ADIM); i += 256) {
        int r = i / (AST - ADIM);
        int c = i - r * (AST - ADIM);
        xs[r * AST + ADIM + c] = 0;
    }
    for (int i = tid; i < 16 * 59; i += 256) {   // 118 = 2*59, float2 loads
        int r = i / 59;
        int c = (i - r * 59) * 2;
        float2 v = *(const float2*)(an + (size_t)(base + r) * ADIM + c);
        xs[r * AST + c]     = f2bf(v.x);
        xs[r * AST + c + 1] = f2bf(v.y);
    }
    __syncthreads();
    const int wave = tid >> 6, lane = tid & 63;
    const int m = lane & 15, quad = lane >> 4;
    bf8_t afrag[4];
    #pragma unroll
    for (int s = 0; s < 4; ++s)
        afrag[s] = *(const bf8_t*)&xs[m * AST + s * 32 + quad * 8];
    const int colbase = wave * 64;
    #pragma unroll
    for (int ct = 0; ct < 4; ++ct) {
        f4_t acc = (f4_t){0.f, 0.f, 0.f, 0.f};
        const unsigned short* wp = WnT + (size_t)(colbase + ct * 16 + m) * 128 + quad * 8;
        #pragma unroll
        for (int s = 0; s < 4; ++s) {
            bf8_t bfrag = *(const bf8_t*)(wp + s * 32);
            acc = __builtin_amdgcn_mfma_f32_16x16x32_bf16(afrag[s], bfrag, acc, 0, 0, 0);
        }
        int col = colbase + ct * 16 + m;
        float bb = bn[col] + be[col];      // fold b_edge
        #pragma unroll
        for (int r = 0; r < 4; ++r)
            hbf[(size_t)(base + quad * 4 + r) * DIM + col] = f2bf(acc[r] + bb);
    }
}

// ---------- gather: XCD-pinned dim-halves, packed-f32 inner math ----------
// Block B -> XCD B%8. half=(B>>2)&1: XCDs 0-3 touch dims [0,128), XCDs 4-7
// dims [128,256) -> per-XCD working set fits 4 MiB L2. 4 waves/block, 1
// node/wave, 4 edges in flight (sub = lane>>4, 16 lanes x 8 dims each).
// hbf holds h+be, so message = relu(pk_fma(l, w, h')) : 6 VALU / 2 dims.
__global__ __launch_bounds__(256) void gather_k(
    const unsigned short* __restrict__ hbf, const int* __restrict__ cnt,
    const int2* __restrict__ epack, const float* __restrict__ We,
    const float* __restrict__ be, const float* __restrict__ epsp, int layer,
    unsigned short* __restrict__ xbf) {
    const int B = blockIdx.x;                 // grid = 5000
    const int half = (B >> 2) & 1;
    const int k = (B >> 3) * 4 + (B & 3);     // node tile [0, 2500)
    const int wave = threadIdx.x >> 6, lane = threadIdx.x & 63;
    const int node = __builtin_amdgcn_readfirstlane(k * 4 + wave);
    const int sub = lane >> 4;                // which of 4 concurrent edges
    const int dp = half * 128 + (lane & 15) * 8;   // this lane's 8 dims
    float4 wa = *(const float4*)(We + dp);
    float4 wc = *(const float4*)(We + dp + 4);
    f2_t ww[4];
    ww[0] = (f2_t){wa.x, wa.y}; ww[1] = (f2_t){wa.z, wa.w};
    ww[2] = (f2_t){wc.x, wc.y}; ww[3] = (f2_t){wc.z, wc.w};
    const float eps1 = 1.f + epsp[layer];
    float4 ba = *(const float4*)(be + dp);
    float4 bc = *(const float4*)(be + dp + 4);
    f2_t ebe[4];                              // eps1 * be (self-term correction)
    ebe[0] = (f2_t){eps1 * ba.x, eps1 * ba.y};
    ebe[1] = (f2_t){eps1 * ba.z, eps1 * ba.w};
    ebe[2] = (f2_t){eps1 * bc.x, eps1 * bc.y};
    ebe[3] = (f2_t){eps1 * bc.z, eps1 * bc.w};
    f2_t acc2[4];
    #pragma unroll
    for (int i = 0; i < 4; ++i) acc2[i] = (f2_t){0.f, 0.f};
    const unsigned short* hb = hbf + dp;
    const int ce = min(__builtin_amdgcn_readfirstlane(cnt[node << 4]), CAP);
    const int2* ep = epack + node * CAP;
#define GATH(q) { \
    const uint4 ar = *(const uint4*)(hb + (unsigned)(q).x); \
    const float l = __int_as_float((q).y); \
    f2_t lpk; lpk.x = l; lpk.y = l; \
    _Pragma("unroll") \
    for (int p = 0; p < 4; ++p) { \
        unsigned u = (&ar.x)[p]; \
        f2_t h; \
        h.x = __uint_as_float(u << 16); \
        h.y = __uint_as_float(u & 0xffff0000u); \
        f2_t mm = pk_fma(lpk, ww[p], h); \
        mm.x = fmaxf(mm.x, 0.f); \
        mm.y = fmaxf(mm.y, 0.f); \
        acc2[p] = pk_add(acc2[p], mm); \
    } }
    int t = 0;
    for (; t + 7 < ce; t += 8) {
        int2 qa = ep[t + sub], qb = ep[t + 4 + sub];
        GATH(qa) GATH(qb)
    }
    for (; t + 3 < ce; t += 4) {
        int2 q = ep[t + sub];
        GATH(q)
    }
    if (t < ce && t + sub < ce) {             // partial group: exec-masked
        int2 q = ep[t + sub];
        GATH(q)
    }
#undef GATH
    // reduce the 4 edge-groups (same dims) across quarter-waves
    #pragma unroll
    for (int p = 0; p < 4; ++p) {
        acc2[p].x += __shfl(acc2[p].x, lane ^ 16, 64);
        acc2[p].y += __shfl(acc2[p].y, lane ^ 16, 64);
        acc2[p].x += __shfl(acc2[p].x, lane ^ 32, 64);
        acc2[p].y += __shfl(acc2[p].y, lane ^ 32, 64);
    }
    if (sub == 0) {
        // x = (1+eps)h + agg, with h = h' - be  ->  x = eps1*h' + (acc - eps1*be)
        const uint4 hr = *(const uint4*)(hbf + (size_t)node * DIM + dp);
        bf8_t o;
        #pragma unroll
        for (int p = 0; p < 4; ++p) {
            unsigned u = (&hr.x)[p];
            float hlo = __uint_as_float(u << 16);
            float hhi = __uint_as_float(u & 0xffff0000u);
            o[2 * p]     = (short)f2bf(fmaf(eps1, hlo, acc2[p].x - ebe[p].x));
            o[2 * p + 1] = (short)f2bf(fmaf(eps1, hhi, acc2[p].y - ebe[p].y));
        }
        *(bf8_t*)(xbf + (size_t)node * DIM + dp) = o;
    }
}

// ---------- MFMA node update: block = 16 rows x 128 cols (grid 1250) ----------
// do_pool=0: writes hout = x@W + b + be (b_edge folded for next gather)
// do_pool=1: pools x@W + b into feat via atomics
#define XST 264   // LDS row stride (ushorts)
__global__ __launch_bounds__(256) void update_k(
    const unsigned short* __restrict__ xbf,
    const unsigned short* __restrict__ WT, const float* __restrict__ b,
    const float* __restrict__ be, unsigned short* __restrict__ hout,
    const int* __restrict__ gid, float* __restrict__ feat, int do_pool) {
    __shared__ __attribute__((aligned(16))) unsigned short xs[16 * XST];
    __shared__ int gids[16];
    const int rb = blockIdx.x >> 1;
    const int halfc = blockIdx.x & 1;
    const int base = rb * 16;
    const int tid = threadIdx.x;
    #pragma unroll
    for (int cch = tid; cch < 512; cch += 256) {     // 16 rows x 32 chunks of 8
        int rr = cch >> 5, k0 = (cch & 31) * 8;
        *(bf8_t*)&xs[rr * XST + k0] = *(const bf8_t*)(xbf + (size_t)(base + rr) * DIM + k0);
    }
    if (do_pool && tid < 16) gids[tid] = gid[base + tid];
    __syncthreads();
    const int wave = tid >> 6, lane = tid & 63;
    const int m = lane & 15, quad = lane >> 4;
    bf8_t afrag[8];
    #pragma unroll
    for (int s = 0; s < 8; ++s)
        afrag[s] = *(const bf8_t*)&xs[m * XST + s * 32 + quad * 8];
    const int colbase = halfc * 128 + wave * 32;
    #pragma unroll
    for (int ct = 0; ct < 2; ++ct) {
        const int col = colbase + ct * 16 + m;
        f4_t acc2 = (f4_t){0.f, 0.f, 0.f, 0.f};
        const unsigned short* wp = WT + (size_t)col * DIM + quad * 8;
        #pragma unroll
        for (int s = 0; s < 8; ++s) {
            bf8_t bfrag = *(const bf8_t*)(wp + s * 32);
            acc2 = __builtin_amdgcn_mfma_f32_16x16x32_bf16(afrag[s], bfrag, acc2, 0, 0, 0);
        }
        if (!do_pool) {
            const float bb = b[col] + be[col];   // fold b_edge for next gather
            #pragma unroll
            for (int r = 0; r < 4; ++r)
                hout[(size_t)(base + quad * 4 + r) * DIM + col] = f2bf(acc2[r] + bb);
        } else {
            const float bb = b[col];
            if (gids[0] == gids[15]) {
                float v = acc2[0] + acc2[1] + acc2[2] + acc2[3] + 4.f * bb;
                v += __shfl(v, lane ^ 16, 64);
                v += __shfl(v, lane ^ 32, 64);   // sum across the 4 quads
                if (quad == 0) atomicAdd(&feat[(size_t)gids[0] * DIM + col], v);
            } else {
                float run = 0.f;
                int cur = gids[quad * 4];
                #pragma unroll
                for (int r = 0; r < 4; ++r) {
                    int g = gids[quad * 4 + r];
                    if (g != cur) {
                        atomicAdd(&feat[(size_t)cur * DIM + col], run);
                        run = 0.f;
                        cur = g;
                    }
                    run += acc2[r] + bb;
                }
                atomicAdd(&feat[(size_t)cur * DIM + col], run);
            }
        }
    }
}

// ---------- fused global minmax + normalize + head (one block per graph) ----------
__global__ __launch_bounds__(256) void headmm_k(
    const float* __restrict__ feat, const float* __restrict__ Wm,
    const float* __restrict__ bm, const float* __restrict__ epsp,
    float* __restrict__ out) {
    __shared__ float frow[DIM];
    __shared__ float smn[4], smx[4], sMn, sMx;
    const int g = blockIdx.x;
    const int tid = threadIdx.x;
    float mn = 3.4e38f, mx = -3.4e38f;
    for (int i = tid; i < N_GRAPHS * DIM; i += 256) {
        float v = feat[i];
        mn = fminf(mn, v);
        mx = fmaxf(mx, v);
    }
    frow[tid] = feat[g * DIM + tid];
    #pragma unroll
    for (int off = 32; off > 0; off >>= 1) {
        mn = fminf(mn, __shfl_down(mn, off, 64));
        mx = fmaxf(mx, __shfl_down(mx, off, 64));
    }
    const int wave = tid >> 6, lane = tid & 63;
    if (lane == 0) { smn[wave] = mn; smx[wave] = mx; }
    __syncthreads();
    if (tid == 0) {
        sMn = fminf(fminf(smn[0], smn[1]), fminf(smn[2], smn[3]));
        sMx = fmaxf(fmaxf(smx[0], smx[1]), fmaxf(smx[2], smx[3]));
    }
    __syncthreads();
    if (tid < OUTD) {
        const float mnv = sMn;
        const float inv = 1.f / (epsp[0] + sMx - mnv);
        float acc = 0.f;
        for (int d = 0; d < DIM; ++d)
            acc += (frow[d] - mnv) * Wm[d * OUTD + tid];
        out[g * OUTD + tid] = acc * inv + bm[tid];
    }
}

extern "C" void kernel_launch(void* const* d_in, const int* in_sizes, int n_in,
                              void* d_out, int out_size, void* d_ws, size_t ws_size,
                              hipStream_t stream) {
    const float* atomic_num = (const float*)d_in[0];
    const float* length     = (const float*)d_in[1];
    const int*   src        = (const int*)d_in[2];
    const int*   dst        = (const int*)d_in[3];
    const int*   gid        = (const int*)d_in[4];
    const float* W_node     = (const float*)d_in[5];
    const float* b_node     = (const float*)d_in[6];
    const float* W_edge     = (const float*)d_in[7];
    const float* b_edge     = (const float*)d_in[8];
    const float* gine_eps   = (const float*)d_in[9];
    const float* W_gnn      = (const float*)d_in[10];
    const float* b_gnn      = (const float*)d_in[11];
    const float* eps_param  = (const float*)d_in[12];
    const float* W_mlp      = (const float*)d_in[13];
    const float* b_mlp      = (const float*)d_in[14];
    float* out = (float*)d_out;

    // workspace (~24 MB). feat+cnt adjacent -> one memset zeroes both.
    float* feat = (float*)d_ws;                                   // G*D   (64 KB)
    int* cnt    = (int*)(feat + (size_t)N_GRAPHS * DIM);          // N*CURPAD (640 KB)
    int2* epack = (int2*)(cnt + (size_t)N_NODES * CURPAD);        // N*CAP
    unsigned short* hbf0 = (unsigned short*)(epack + (size_t)N_NODES * CAP); // [N][256]
    unsigned short* hbf1 = hbf0 + (size_t)N_NODES * DIM;          // [N][256]
    unsigned short* xbf  = hbf1 + (size_t)N_NODES * DIM;          // [N][256]
    unsigned short* WnT  = xbf + (size_t)N_NODES * DIM;           // 256*128
    unsigned short* WgT  = WnT + 256 * 128;                       // 2*256*256

    hipMemsetAsync(d_ws, 0,
                   (size_t)N_GRAPHS * DIM * 4 + (size_t)N_NODES * CURPAD * 4,
                   stream);
    setup_k<<<1250 + 640, 256, 0, stream>>>(
        src, dst, length, W_node, W_gnn, WnT, WgT, cnt, epack);
    node_embed_k<<<N_NODES / 16, 256, 0, stream>>>(
        atomic_num, WnT, b_node, b_edge, hbf0);

    // GINE layer 0: hbf0 -> xbf -> hbf1
    gather_k<<<5000, 256, 0, stream>>>(
        hbf0, cnt, epack, W_edge, b_edge, gine_eps, 0, xbf);
    update_k<<<(N_NODES / 16) * 2, 256, 0, stream>>>(
        xbf, WgT, b_gnn, b_edge, hbf1, gid, feat, 0);
    // GINE layer 1: hbf1 -> xbf -> feat (pooled)
    gather_k<<<5000, 256, 0, stream>>>(
        hbf1, cnt, epack, W_edge, b_edge, gine_eps, 1, xbf);
    update_k<<<(N_NODES / 16) * 2, 256, 0, stream>>>(
        xbf, WgT + 256 * 256, b_gnn + DIM, b_edge, hbf0, gid, feat, 1);

    // fused minmax + normalize + head
    headmm_k<<<N_GRAPHS, 256, 0, stream>>>(feat, W_mlp, b_mlp, eps_param, out);
}